// Round 5
// baseline (664.455 us; speedup 1.0000x reference)
//
#include <hip/hip_runtime.h>
#include <hip/hip_bf16.h>
#include <stdint.h>

// RoPEDemoAttention on MI355X (gfx950)
// B=4, S=4096, D=256. fp32 in/out.
// K0: split fp32 -> bf16 hi/lo + RoPE cos/sin table.
// K1: Q/K/V projections via 3-pass split-bf16 MFMA + RoPE.
// K2a (split-K): 512 blocks = (b, khalf, 64-q-tile); 32-key tiles, dbuf LDS,
//     one barrier/tile; e-bf16 -> EB (top half of weights region);
//     PV partial (f32, unnormalized) -> bottom half; rowsum half -> lsum_g.
// K2b: 256 blocks; out = (po0+po1)/lsum; then 3-phase in-place sweep
//     e-bf16 -> normalized f32 weights (rows 48-63 via LDS).
//     R5 fix: sweep slots now cover 16 elements (was 8 -> half of every
//     row kept stale PV partials, weights absmax 2816).

#define B_ 4
#define S_ 4096
#define D_ 256
#define NQ 4194304   // B_*S_*D_
#define NW 65536     // D_*D_
#define NTAB 524288  // S_*128 table entries (cos,sin pairs)

typedef __attribute__((ext_vector_type(4))) float f32x4;
typedef __attribute__((ext_vector_type(8))) short short8;
typedef __attribute__((ext_vector_type(4))) short short4v;
typedef __attribute__((ext_vector_type(4))) unsigned uint32x4;

__device__ __forceinline__ short f2bf(float f) {
  unsigned u = __builtin_bit_cast(unsigned, f);
  u += 0x7fffu + ((u >> 16) & 1u);   // RNE
  return (short)(u >> 16);
}
__device__ __forceinline__ float bf2f(short h) {
  unsigned u = ((unsigned)(unsigned short)h) << 16;
  return __builtin_bit_cast(float, u);
}

__device__ __forceinline__ void gload16(const void* g, void* l) {
  __builtin_amdgcn_global_load_lds(
      (const __attribute__((address_space(1))) unsigned*)g,
      (__attribute__((address_space(3))) unsigned*)l, 16, 0, 0);
}

// convert 16 bf16 e-values -> 16 normalized f32 weights
__device__ __forceinline__ void cvt16(const char* er, float* wr, int k0, float rinv) {
  short8 ev0 = *(const short8*)(er + (size_t)k0 * 2);
  short8 ev1 = *(const short8*)(er + (size_t)k0 * 2 + 16);
  f32x4 o0, o1, o2, o3;
#pragma unroll
  for (int j = 0; j < 4; ++j) {
    o0[j] = bf2f(ev0[j]) * rinv;
    o1[j] = bf2f(ev0[4 + j]) * rinv;
    o2[j] = bf2f(ev1[j]) * rinv;
    o3[j] = bf2f(ev1[4 + j]) * rinv;
  }
  *(f32x4*)(wr + k0) = o0;
  *(f32x4*)(wr + k0 + 4) = o1;
  *(f32x4*)(wr + k0 + 8) = o2;
  *(f32x4*)(wr + k0 + 12) = o3;
}

// ------------------------------------------------ K0: split + RoPE table
__global__ __launch_bounds__(256) void k0_split(
    const float* __restrict__ x, const float* __restrict__ wq,
    const float* __restrict__ wk, const float* __restrict__ wv,
    short* __restrict__ xh, short* __restrict__ xl,
    short* __restrict__ wh, short* __restrict__ wl,
    float* __restrict__ ctab) {
  int idx = blockIdx.x * 256 + threadIdx.x;  // grid = NQ + 3*NW + NTAB
  if (idx < NQ) {
    float v = x[idx];
    short hi = f2bf(v);
    xh[idx] = hi;
    xl[idx] = f2bf(v - bf2f(hi));
  } else if (idx < NQ + 3 * NW) {
    int r = idx - NQ;
    int m = r >> 16;
    int e = r & (NW - 1);
    const float* w = (m == 0) ? wq : (m == 1) ? wk : wv;
    float v = w[e];
    short hi = f2bf(v);
    wh[r] = hi;
    wl[r] = f2bf(v - bf2f(hi));
  } else {
    int t = idx - NQ - 3 * NW;          // t < NTAB
    int s = t >> 7, j = t & 127;
    float invf = __expf(-0.07195578415606394f * (float)j); // 10000^(-j/128)
    float sn, cs;
    sincosf((float)s * invf, &sn, &cs);
    ctab[2 * t] = cs;
    ctab[2 * t + 1] = sn;
  }
}

// ------------------------------------------------------- K1: proj + RoPE
__global__ __launch_bounds__(256) void k1_proj(
    const short* __restrict__ xh, const short* __restrict__ xl,
    const short* __restrict__ wh, const short* __restrict__ wl,
    const float* __restrict__ ctab,
    short* __restrict__ qh, short* __restrict__ ql,
    short* __restrict__ kh, short* __restrict__ kl,
    short* __restrict__ vt) {
  const int m = blockIdx.y;                 // 0=q 1=k 2=v
  const int b = blockIdx.x >> 6;
  const int sbase = (blockIdx.x & 63) << 6; // 64-row tile
  const int tid = threadIdx.x;
  const int w = tid >> 6;
  const int lane = tid & 63;
  const int lr = lane & 15;
  const int g = lane >> 4;

  const int srow = sbase + w * 16 + lr;     // A-frag row
  const short* xhp = xh + ((size_t)(b * S_ + srow)) * D_;
  const short* xlp = xl + ((size_t)(b * S_ + srow)) * D_;
  const short* whm = wh + m * NW;
  const short* wlm = wl + m * NW;

  f32x4 acc[16];
#pragma unroll
  for (int i = 0; i < 16; ++i) acc[i] = (f32x4)0.f;

#pragma unroll
  for (int dc = 0; dc < 8; ++dc) {
    const int d = dc * 32 + g * 8;
    short8 ah = *(const short8*)(xhp + d);
    short8 al = *(const short8*)(xlp + d);
#pragma unroll
    for (int ct = 0; ct < 16; ++ct) {
      const int e = ct * 16 + lr;
      short8 bh = *(const short8*)(whm + e * D_ + d);
      short8 bl = *(const short8*)(wlm + e * D_ + d);
      acc[ct] = __builtin_amdgcn_mfma_f32_16x16x32_bf16(ah, bh, acc[ct], 0, 0, 0);
      acc[ct] = __builtin_amdgcn_mfma_f32_16x16x32_bf16(ah, bl, acc[ct], 0, 0, 0);
      acc[ct] = __builtin_amdgcn_mfma_f32_16x16x32_bf16(al, bh, acc[ct], 0, 0, 0);
    }
  }

  const int s0 = sbase + w * 16 + g * 4;    // C/D row base
  if (m == 2) {
#pragma unroll
    for (int ct = 0; ct < 16; ++ct) {
      const int e = ct * 16 + lr;
      short4v pk;
#pragma unroll
      for (int r = 0; r < 4; ++r) pk[r] = f2bf(acc[ct][r]);
      *(short4v*)(vt + ((size_t)(b * D_ + e)) * S_ + s0) = pk;
    }
  } else {
    short* oh = (m == 0) ? qh : kh;
    short* ol = (m == 0) ? ql : kl;
#pragma unroll
    for (int ct = 0; ct < 16; ++ct) {
      const int e = ct * 16 + lr;
      const float sgn = (e & 1) ? 1.0f : -1.0f;  // rotate_half sign
#pragma unroll
      for (int r = 0; r < 4; ++r) {
        float v = acc[ct][r];
        float p = __shfl_xor(v, 1, 64);          // partner e^1, same s
        const float2 cs2 = *(const float2*)(ctab + ((size_t)((s0 + r) << 7) + (e & 127)) * 2);
        float q2 = v * cs2.x + sgn * p * cs2.y;
        short hi = f2bf(q2);
        size_t off = ((size_t)(b * S_ + s0 + r)) * D_ + e;
        oh[off] = hi;
        ol[off] = f2bf(q2 - bf2f(hi));
      }
    }
  }
}

// ---------------- K2a: split-K scores + e-store + PV partial, 2 blocks/CU
__global__ __launch_bounds__(512, 4) void k2a(
    const short* __restrict__ qh, const short* __restrict__ ql,
    const short* __restrict__ kh, const short* __restrict__ kl,
    const short* __restrict__ vt,
    float* __restrict__ wts, float* __restrict__ lsum_g) {
  __shared__ __align__(16) char kbuf[65536];    // [2][Khi 16K | Klo 16K]
  __shared__ __align__(16) char etile[2][4096]; // e bf16 [64 q][32 k], swz
  __shared__ float part[2][64];

  const int bid = blockIdx.x;        // 512 blocks
  const int grp = bid & 7;           // XCD group = (b, khalf)
  const int b = grp >> 1;
  const int khalf = grp & 1;
  const int qbase = (bid >> 3) << 6; // 64 q-tiles per group
  const int tid = threadIdx.x;
  const int w = tid >> 6;            // 8 waves
  const int lane = tid & 63;
  const int lr = lane & 15;
  const int g = lane >> 4;
  const int qg = w & 3;              // q-group: 16 rows
  const int wk2 = w >> 2;            // key-group: 16 of 32-key tile
  const int dh = w >> 2;             // PV: d-half (128)

  // Q hi/lo fragments (B-operand), registers for all tiles
  short8 qfh[8], qfl[8];
  {
    const int qrow = qbase + qg * 16 + lr;
    const short* ph = qh + ((size_t)(b * S_ + qrow)) * D_;
    const short* pl = ql + ((size_t)(b * S_ + qrow)) * D_;
#pragma unroll
    for (int dc = 0; dc < 8; ++dc) {
      qfh[dc] = *(const short8*)(ph + dc * 32 + g * 8);
      qfl[dc] = *(const short8*)(pl + dc * 32 + g * 8);
    }
  }

  f32x4 acc = (f32x4)0.f;
  f32x4 accv[8];
#pragma unroll
  for (int i = 0; i < 8; ++i) accv[i] = (f32x4)0.f;
  float rs = 0.f;

  const char* khb = (const char*)(kh + ((size_t)b * S_ + khalf * 2048) * D_);
  const char* klb = (const char*)(kl + ((size_t)b * S_ + khalf * 2048) * D_);
  const short* vtb = vt + (size_t)b * D_ * S_;
  const int keyl = wk2 * 16 + lr;          // local key row of A-frag
  const int swx = (lane & 7) << 4;         // K-LDS swizzle: (key&7)<<4

  // weights region of this q-tile (1 MiB)
  float* WBf = wts + ((size_t)(b * S_ + qbase)) * S_;
  char* EB = (char*)WBf + 524288;          // e-bf16 scratch (top half)

  // prologue: stage tile 0 into kbuf[0]
#pragma unroll
  for (int i = 0; i < 2; ++i) {
    const int p = i * 8192 + tid * 16;
    const int xo = p ^ (((p >> 9) & 7) << 4);
    gload16(khb + xo, kbuf + p);
    gload16(klb + xo, kbuf + 16384 + p);
  }
  __syncthreads();

  for (int kt = 0; kt < 64; ++kt) {
    const int cur = kt & 1;
    const char* kb = kbuf + cur * 32768;

    // 1. stage next tile into other buffer
    if (kt < 63) {
      const char* sh = khb + (size_t)(kt + 1) * 16384;
      const char* sl = klb + (size_t)(kt + 1) * 16384;
      char* kn = kbuf + (cur ^ 1) * 32768;
#pragma unroll
      for (int i = 0; i < 2; ++i) {
        const int p = i * 8192 + tid * 16;
        const int xo = p ^ (((p >> 9) & 7) << 4);
        gload16(sh + xo, kn + p);
        gload16(sl + xo, kn + 16384 + p);
      }
    }

    // 2. e-copy + PV of PREVIOUS tile
    if (kt > 0) {
      const char* et = etile[cur ^ 1];
      {
        const int row = tid >> 3, cb = (tid & 7) * 8;
        uint2 v = *(const uint2*)(et + (row * 64 + (cb ^ ((row & 3) << 4))));
        *(uint2*)(EB + (size_t)row * 8192 + khalf * 4096 + (kt - 1) * 64 + cb) = v;
      }
      __builtin_amdgcn_s_setprio(1);
      short8 ea;
      {
        const int row = qg * 16 + lr;
        ea = *(const short8*)(et + (row * 64 + ((g * 16) ^ ((row & 3) << 4))));
      }
#pragma unroll
      for (int dt = 0; dt < 8; ++dt) {
        const int d = dh * 128 + dt * 16 + lr;
        short8 vb = *(const short8*)(vtb + (size_t)d * S_ + khalf * 2048 + (kt - 1) * 32 + g * 8);
        accv[dt] = __builtin_amdgcn_mfma_f32_16x16x32_bf16(ea, vb, accv[dt], 0, 0, 0);
      }
      __builtin_amdgcn_s_setprio(0);
    }

    // 3. scores: 3-pass split bf16, S^T = K * Q^T
    __builtin_amdgcn_s_setprio(1);
#pragma unroll
    for (int dc = 0; dc < 8; ++dc) {
      const int x = (keyl * 512 + dc * 64 + g * 16) ^ swx;
      short8 afh = *(const short8*)(kb + x);
      short8 afl = *(const short8*)(kb + 16384 + x);
      acc = __builtin_amdgcn_mfma_f32_16x16x32_bf16(afh, qfh[dc], acc, 0, 0, 0);
      acc = __builtin_amdgcn_mfma_f32_16x16x32_bf16(afh, qfl[dc], acc, 0, 0, 0);
      acc = __builtin_amdgcn_mfma_f32_16x16x32_bf16(afl, qfh[dc], acc, 0, 0, 0);
    }
    __builtin_amdgcn_s_setprio(0);

    // 4. e = exp(s/16) -> etile[cur] + rowsum
    {
      f32x4 e;
#pragma unroll
      for (int r = 0; r < 4; ++r) e[r] = __expf(acc[r] * 0.0625f);
      rs += e[0] + e[1] + e[2] + e[3];
      unsigned lo = (unsigned)(unsigned short)f2bf(e[0]) |
                    ((unsigned)(unsigned short)f2bf(e[1]) << 16);
      unsigned hi2 = (unsigned)(unsigned short)f2bf(e[2]) |
                     ((unsigned)(unsigned short)f2bf(e[3]) << 16);
      const int row = qg * 16 + lr;                 // q-local
      const int cb = (wk2 * 16 + g * 4) * 2;        // key-local bytes
      *(uint2*)(etile[cur] + (row * 64 + (cb ^ ((row & 3) << 4)))) = make_uint2(lo, hi2);
      acc = (f32x4)0.f;
    }
    __syncthreads();   // ONE barrier per tile
  }

  // ---- tail: e-copy + PV of tile 63 (etile[1])
  {
    const char* et = etile[1];
    {
      const int row = tid >> 3, cb = (tid & 7) * 8;
      uint2 v = *(const uint2*)(et + (row * 64 + (cb ^ ((row & 3) << 4))));
      *(uint2*)(EB + (size_t)row * 8192 + khalf * 4096 + 63 * 64 + cb) = v;
    }
    short8 ea;
    {
      const int row = qg * 16 + lr;
      ea = *(const short8*)(et + (row * 64 + ((g * 16) ^ ((row & 3) << 4))));
    }
#pragma unroll
    for (int dt = 0; dt < 8; ++dt) {
      const int d = dh * 128 + dt * 16 + lr;
      short8 vb = *(const short8*)(vtb + (size_t)d * S_ + khalf * 2048 + 63 * 32 + g * 8);
      accv[dt] = __builtin_amdgcn_mfma_f32_16x16x32_bf16(ea, vb, accv[dt], 0, 0, 0);
    }
  }

  // ---- rowsum partials: reduce over g then over wk2
  rs += __shfl_xor(rs, 16, 64);
  rs += __shfl_xor(rs, 32, 64);
  if (lane < 16) part[wk2][qg * 16 + lane] = rs;
  __syncthreads();
  if (tid < 64)
    lsum_g[khalf * 16384 + b * S_ + qbase + tid] = part[0][tid] + part[1][tid];

  // ---- PV partial store into bottom half of weights region
  {
    float* pob = WBf + khalf * 16384;   // 64 KB region
#pragma unroll
    for (int dt = 0; dt < 8; ++dt) {
      const int d = dh * 128 + dt * 16 + lr;
#pragma unroll
      for (int r = 0; r < 4; ++r) {
        const int q = qg * 16 + g * 4 + r;
        pob[q * 256 + d] = accv[dt][r];
      }
    }
  }
}

// ------------- K2b: combine PV halves -> out; sweep e-bf16 -> weights
__global__ __launch_bounds__(512) void k2b(
    float* __restrict__ wts, const float* __restrict__ lsum_g,
    float* __restrict__ out) {
  __shared__ float lsum_l[64];
  __shared__ __align__(16) char ebuf[131072];   // e rows 48..63

  const int bid = blockIdx.x;        // 256 blocks
  const int b = bid >> 6;
  const int qbase = (bid & 63) << 6;
  const int tid = threadIdx.x;

  float* WBf = wts + ((size_t)(b * S_ + qbase)) * S_;
  char* WB = (char*)WBf;
  const char* EB = WB + 524288;

  if (tid < 64)
    lsum_l[tid] = lsum_g[b * S_ + qbase + tid] + lsum_g[16384 + b * S_ + qbase + tid];
  __syncthreads();

  // phase 0: out = (po0 + po1) * rinv ; pre-copy e rows 48..63 -> LDS
  {
    const int q = tid >> 3;
    const int dg = (tid & 7) * 32;
    const float rinv = 1.0f / lsum_l[q];
    const float* po0 = WBf + q * 256 + dg;
    const float* po1 = po0 + 16384;
    float* ob = out + ((size_t)(b * S_ + qbase + q)) * D_ + dg;
#pragma unroll
    for (int i = 0; i < 8; ++i) {
      f32x4 a = *(const f32x4*)(po0 + i * 4);
      f32x4 c = *(const f32x4*)(po1 + i * 4);
#pragma unroll
      for (int j = 0; j < 4; ++j) a[j] = (a[j] + c[j]) * rinv;
      *(f32x4*)(ob + i * 4) = a;
    }
#pragma unroll
    for (int i = 0; i < 16; ++i) {
      const int p = i * 8192 + tid * 16;
      *(uint32x4*)(ebuf + p) = *(const uint32x4*)(EB + (size_t)48 * 8192 + p);
    }
  }
  __syncthreads();

  // phase 1: w-rows 0..31 (overwrite po region; sources e0..31 untouched)
  // 16 threads/row x 16 chunks x 16 elems = 4096 per row
  {
    const int row = tid >> 4;
    const int ch = tid & 15;
    const float rinv = 1.0f / lsum_l[row];
    const char* er = EB + (size_t)row * 8192;
    float* wr = WBf + (size_t)row * 4096;
#pragma unroll 2
    for (int cc = 0; cc < 16; ++cc)
      cvt16(er, wr, cc * 256 + ch * 16, rinv);
  }
  __syncthreads();

  // phase 2: w-rows 32..47 (overwrite e0..31, consumed; sources e32..47)
  // 32 threads/row x 8 chunks x 16 elems = 4096 per row
  {
    const int row = 32 + (tid >> 5);
    const int ch = tid & 31;
    const float rinv = 1.0f / lsum_l[row];
    const char* er = EB + (size_t)row * 8192;
    float* wr = WBf + (size_t)row * 4096;
#pragma unroll 2
    for (int cc = 0; cc < 8; ++cc)
      cvt16(er, wr, cc * 512 + ch * 16, rinv);
  }
  __syncthreads();

  // phase 3: w-rows 48..63 from LDS copy
  {
    const int row = 48 + (tid >> 5);
    const int ch = tid & 31;
    const float rinv = 1.0f / lsum_l[row];
    const char* er = ebuf + (size_t)(row - 48) * 8192;
    float* wr = WBf + (size_t)row * 4096;
#pragma unroll 2
    for (int cc = 0; cc < 8; ++cc)
      cvt16(er, wr, cc * 512 + ch * 16, rinv);
  }
}

// ---------------------------------------------------------------- launch
extern "C" void kernel_launch(void* const* d_in, const int* in_sizes, int n_in,
                              void* d_out, int out_size, void* d_ws, size_t ws_size,
                              hipStream_t stream) {
  const float* x  = (const float*)d_in[0];
  const float* wq = (const float*)d_in[1];
  const float* wk = (const float*)d_in[2];
  const float* wv = (const float*)d_in[3];

  float* out = (float*)d_out;                    // [B][S][D]
  float* wts = out + (size_t)B_ * S_ * D_;       // [B][S][S]

  // workspace layout (~63.7 MB)
  short* xh = (short*)d_ws;
  short* xl = xh + NQ;
  short* qh = xl + NQ;
  short* ql = qh + NQ;
  short* kh = ql + NQ;
  short* kl = kh + NQ;
  short* vt = kl + NQ;                 // [B][D][S] bf16
  short* wh = vt + NQ;                 // [3][D][D] bf16
  short* wl = wh + 3 * NW;
  float* ctab = (float*)(wl + 3 * NW); // [S][128] (cos,sin) fp32
  float* lsum_g = ctab + 2 * NTAB;     // [2][B*S] fp32

  k0_split<<<dim3((NQ + 3 * NW + NTAB) / 256), 256, 0, stream>>>(
      x, wq, wk, wv, xh, xl, wh, wl, ctab);
  k1_proj<<<dim3(B_ * S_ / 64, 3), 256, 0, stream>>>(
      xh, xl, wh, wl, ctab, qh, ql, kh, kl, vt);
  k2a<<<dim3(512), 512, 0, stream>>>(
      qh, ql, kh, kl, vt, wts, lsum_g);
  k2b<<<dim3(256), 512, 0, stream>>>(
      wts, lsum_g, out);
}

// Round 6
// 513.889 us; speedup vs baseline: 1.2930x; 1.2930x over previous
//
#include <hip/hip_runtime.h>
#include <hip/hip_bf16.h>
#include <stdint.h>

// RoPEDemoAttention on MI355X (gfx950)
// B=4, S=4096, D=256. fp32 in/out.
// K0: split fp32 -> bf16 hi/lo + RoPE cos/sin table.
// K1: Q/K/V projections via 3-pass split-bf16 MFMA + RoPE; q/k stores go
//     through an LDS transpose tile -> coalesced short8 stores (R6).
// K2 (fused, counted-vmcnt pipeline, R6): per (b, 64-q-tile), 64-key tiles:
//   raw s_barrier + manual s_waitcnt vmcnt(N) -- staging loads stay in
//   flight across barriers (never drained to 0 in the loop):
//     A: vmcnt(N) -> B: s_barrier -> V-loads(kt) -> scores(kt) -> exp ->
//     lgkmcnt(0) -> s_barrier -> stage(kt+2) -> ecopy(kt) -> PV(kt)
//   then rowsums, normalized out, 6-phase in-place e->weights sweep.

#define B_ 4
#define S_ 4096
#define D_ 256
#define NQ 4194304   // B_*S_*D_
#define NW 65536     // D_*D_
#define NTAB 524288  // S_*128 table entries (cos,sin pairs)

typedef __attribute__((ext_vector_type(4))) float f32x4;
typedef __attribute__((ext_vector_type(8))) short short8;
typedef __attribute__((ext_vector_type(4))) short short4v;
typedef __attribute__((ext_vector_type(4))) unsigned uint32x4;

__device__ __forceinline__ short f2bf(float f) {
  unsigned u = __builtin_bit_cast(unsigned, f);
  u += 0x7fffu + ((u >> 16) & 1u);   // RNE
  return (short)(u >> 16);
}
__device__ __forceinline__ float bf2f(short h) {
  unsigned u = ((unsigned)(unsigned short)h) << 16;
  return __builtin_bit_cast(float, u);
}

__device__ __forceinline__ void gload16(const void* g, void* l) {
  __builtin_amdgcn_global_load_lds(
      (const __attribute__((address_space(1))) unsigned*)g,
      (__attribute__((address_space(3))) unsigned*)l, 16, 0, 0);
}

// ------------------------------------------------ K0: split + RoPE table
__global__ __launch_bounds__(256) void k0_split(
    const float* __restrict__ x, const float* __restrict__ wq,
    const float* __restrict__ wk, const float* __restrict__ wv,
    short* __restrict__ xh, short* __restrict__ xl,
    short* __restrict__ wh, short* __restrict__ wl,
    float* __restrict__ ctab) {
  int idx = blockIdx.x * 256 + threadIdx.x;  // grid = NQ + 3*NW + NTAB
  if (idx < NQ) {
    float v = x[idx];
    short hi = f2bf(v);
    xh[idx] = hi;
    xl[idx] = f2bf(v - bf2f(hi));
  } else if (idx < NQ + 3 * NW) {
    int r = idx - NQ;
    int m = r >> 16;
    int e = r & (NW - 1);
    const float* w = (m == 0) ? wq : (m == 1) ? wk : wv;
    float v = w[e];
    short hi = f2bf(v);
    wh[r] = hi;
    wl[r] = f2bf(v - bf2f(hi));
  } else {
    int t = idx - NQ - 3 * NW;          // t < NTAB
    int s = t >> 7, j = t & 127;
    float invf = __expf(-0.07195578415606394f * (float)j); // 10000^(-j/128)
    float sn, cs;
    sincosf((float)s * invf, &sn, &cs);
    ctab[2 * t] = cs;
    ctab[2 * t + 1] = sn;
  }
}

// ------------------------------------------------------- K1: proj + RoPE
__global__ __launch_bounds__(256) void k1_proj(
    const short* __restrict__ xh, const short* __restrict__ xl,
    const short* __restrict__ wh, const short* __restrict__ wl,
    const float* __restrict__ ctab,
    short* __restrict__ qh, short* __restrict__ ql,
    short* __restrict__ kh, short* __restrict__ kl,
    short* __restrict__ vt) {
  __shared__ short tbuf[16384];             // 32KB transpose tile [64][256]
  const int m = blockIdx.y;                 // 0=q 1=k 2=v
  const int b = blockIdx.x >> 6;
  const int sbase = (blockIdx.x & 63) << 6; // 64-row tile
  const int tid = threadIdx.x;
  const int w = tid >> 6;
  const int lane = tid & 63;
  const int lr = lane & 15;
  const int g = lane >> 4;

  const int srow = sbase + w * 16 + lr;     // A-frag row
  const short* xhp = xh + ((size_t)(b * S_ + srow)) * D_;
  const short* xlp = xl + ((size_t)(b * S_ + srow)) * D_;
  const short* whm = wh + m * NW;
  const short* wlm = wl + m * NW;

  f32x4 acc[16];
#pragma unroll
  for (int i = 0; i < 16; ++i) acc[i] = (f32x4)0.f;

#pragma unroll
  for (int dc = 0; dc < 8; ++dc) {
    const int d = dc * 32 + g * 8;
    short8 ah = *(const short8*)(xhp + d);
    short8 al = *(const short8*)(xlp + d);
#pragma unroll
    for (int ct = 0; ct < 16; ++ct) {
      const int e = ct * 16 + lr;
      short8 bh = *(const short8*)(whm + e * D_ + d);
      short8 bl = *(const short8*)(wlm + e * D_ + d);
      acc[ct] = __builtin_amdgcn_mfma_f32_16x16x32_bf16(ah, bh, acc[ct], 0, 0, 0);
      acc[ct] = __builtin_amdgcn_mfma_f32_16x16x32_bf16(ah, bl, acc[ct], 0, 0, 0);
      acc[ct] = __builtin_amdgcn_mfma_f32_16x16x32_bf16(al, bh, acc[ct], 0, 0, 0);
    }
  }

  const int s0 = sbase + w * 16 + g * 4;    // C/D row base
  if (m == 2) {
#pragma unroll
    for (int ct = 0; ct < 16; ++ct) {
      const int e = ct * 16 + lr;
      short4v pk;
#pragma unroll
      for (int r = 0; r < 4; ++r) pk[r] = f2bf(acc[ct][r]);
      *(short4v*)(vt + ((size_t)(b * D_ + e)) * S_ + s0) = pk;
    }
  } else {
    short* oh = (m == 0) ? qh : kh;
    short* ol = (m == 0) ? ql : kl;
    // RoPE in place
#pragma unroll
    for (int ct = 0; ct < 16; ++ct) {
      const int e = ct * 16 + lr;
      const float sgn = (e & 1) ? 1.0f : -1.0f;  // rotate_half sign
#pragma unroll
      for (int r = 0; r < 4; ++r) {
        float v = acc[ct][r];
        float p = __shfl_xor(v, 1, 64);          // partner e^1, same s
        const float2 cs2 = *(const float2*)(ctab + ((size_t)((s0 + r) << 7) + (e & 127)) * 2);
        acc[ct][r] = v * cs2.x + sgn * p * cs2.y;
      }
    }
    const int rowb = w * 16 + g * 4;             // s-local row base
    const size_t gbase = ((size_t)(b * S_ + sbase)) * D_;
    // hi pass: LDS transpose -> coalesced short8 stores
#pragma unroll
    for (int ct = 0; ct < 16; ++ct)
#pragma unroll
      for (int r = 0; r < 4; ++r)
        tbuf[(rowb + r) * 256 + ct * 16 + lr] = f2bf(acc[ct][r]);
    __syncthreads();
#pragma unroll
    for (int j = 0; j < 8; ++j) {
      const int L = j * 2048 + tid * 8;
      *(short8*)(oh + gbase + L) = *(const short8*)(tbuf + L);
    }
    __syncthreads();
    // lo pass
#pragma unroll
    for (int ct = 0; ct < 16; ++ct)
#pragma unroll
      for (int r = 0; r < 4; ++r) {
        float q2 = acc[ct][r];
        tbuf[(rowb + r) * 256 + ct * 16 + lr] = f2bf(q2 - bf2f(f2bf(q2)));
      }
    __syncthreads();
#pragma unroll
    for (int j = 0; j < 8; ++j) {
      const int L = j * 2048 + tid * 8;
      *(short8*)(ol + gbase + L) = *(const short8*)(tbuf + L);
    }
  }
}

// ------------- K2 fused: counted-vmcnt pipelined scores + PV + sweep
__global__ __launch_bounds__(512, 1) void k2_fused(
    const short* __restrict__ qh, const short* __restrict__ ql,
    const short* __restrict__ kh, const short* __restrict__ kl,
    const short* __restrict__ vt,
    float* __restrict__ wts, float* __restrict__ out) {
  __shared__ __align__(16) char kbuf[131072];   // [2][Khi 32K | Klo 32K]
  __shared__ __align__(16) char etile[2][8192]; // e bf16 [64][64], swizzled
  __shared__ float part[4][64];
  __shared__ float lsum_l[64];

  const int bid = blockIdx.x;
  const int swz = (bid & 7) * 32 + (bid >> 3); // XCD-contiguous (256 = 8*32)
  const int b = swz >> 6;
  const int qbase = (swz & 63) << 6;
  const int tid = threadIdx.x;
  const int w = tid >> 6;        // 8 waves
  const int lane = tid & 63;
  const int lr = lane & 15;
  const int g = lane >> 4;
  const int wq2 = w & 1;         // scores: which 32 q-rows
  const int wk4 = w >> 1;        // scores: which 16 keys of 64-key tile
  const int qh_pv = w & 1;       // PV: q 32-half
  const int dh_pv = w >> 1;      // PV: d 64-quarter

  // Q hi/lo fragments (B-operand), registers for all 64 k-tiles
  short8 qfh[2][8], qfl[2][8];
#pragma unroll
  for (int qt = 0; qt < 2; ++qt) {
    const int qrow = qbase + wq2 * 32 + qt * 16 + lr;
    const short* ph = qh + ((size_t)(b * S_ + qrow)) * D_;
    const short* pl = ql + ((size_t)(b * S_ + qrow)) * D_;
#pragma unroll
    for (int dc = 0; dc < 8; ++dc) {
      qfh[qt][dc] = *(const short8*)(ph + dc * 32 + g * 8);
      qfl[qt][dc] = *(const short8*)(pl + dc * 32 + g * 8);
    }
  }

  f32x4 acc[2];
  acc[0] = (f32x4)0.f; acc[1] = (f32x4)0.f;
  f32x4 accv[2][4];
#pragma unroll
  for (int qt = 0; qt < 2; ++qt)
#pragma unroll
    for (int dt = 0; dt < 4; ++dt) accv[qt][dt] = (f32x4)0.f;
  float rs[2] = {0.f, 0.f};

  const char* khb = (const char*)(kh + (size_t)b * S_ * D_);
  const char* klb = (const char*)(kl + (size_t)b * S_ * D_);
  const short* vtb = vt + (size_t)b * D_ * S_;
  const int keyl = wk4 * 16 + lr;          // local key row of A-frag
  const int swx = (lane & 7) << 4;         // K-LDS swizzle: (key&7)<<4

  // block's weights region (1 MiB); e-bf16 scratch in its top half
  char* WB = (char*)(wts + ((size_t)(b * S_ + qbase)) * S_);
  char* EB = WB + 524288;

  auto STAGE = [&](int kt, char* dst) {
#pragma unroll
    for (int i = 0; i < 4; ++i) {
      const int p = i * 8192 + tid * 16;
      const int xo = p ^ (((p >> 9) & 7) << 4);
      gload16(khb + (size_t)kt * 32768 + xo, dst + p);
      gload16(klb + (size_t)kt * 32768 + xo, dst + 32768 + p);
    }
  };

  // prologue: stage tiles 0 and 1 (8 gload_lds each per thread)
  STAGE(0, kbuf);
  STAGE(1, kbuf + 65536);

  for (int kt = 0; kt < 64; ++kt) {
    const int cur = kt & 1;
    const char* kb = kbuf + cur * 65536;

    // A: my stage(kt) loads retired (in-order vmcnt; younger ops stay in
    // flight: V loads retire by use, 8 stage(kt+1) + stores may linger)
    if (kt == 0)      asm volatile("s_waitcnt vmcnt(8)" ::: "memory");
    else if (kt == 1) asm volatile("s_waitcnt vmcnt(17)" ::: "memory");
    else if (kt < 63) asm volatile("s_waitcnt vmcnt(18)" ::: "memory");
    else              asm volatile("s_waitcnt vmcnt(10)" ::: "memory");
    __builtin_amdgcn_s_barrier();        // B: tile kt valid block-wide
    __builtin_amdgcn_sched_barrier(0);

    // early V loads for PV(kt) — latency hides under scores
    short8 vb[2][4];
#pragma unroll
    for (int kk = 0; kk < 2; ++kk)
#pragma unroll
      for (int dt = 0; dt < 4; ++dt)
        vb[kk][dt] = *(const short8*)(vtb + (size_t)(dh_pv * 64 + dt * 16 + lr) * S_ + kt * 64 + kk * 32 + g * 8);

    // scores: 3-pass split bf16, S^T = K * Q^T (reads kb)
    __builtin_amdgcn_s_setprio(1);
#pragma unroll
    for (int dc = 0; dc < 8; ++dc) {
      const int x = (keyl * 512 + dc * 64 + g * 16) ^ swx;
      short8 afh = *(const short8*)(kb + x);
      short8 afl = *(const short8*)(kb + 32768 + x);
      acc[0] = __builtin_amdgcn_mfma_f32_16x16x32_bf16(afh, qfh[0][dc], acc[0], 0, 0, 0);
      acc[0] = __builtin_amdgcn_mfma_f32_16x16x32_bf16(afh, qfl[0][dc], acc[0], 0, 0, 0);
      acc[0] = __builtin_amdgcn_mfma_f32_16x16x32_bf16(afl, qfh[0][dc], acc[0], 0, 0, 0);
      acc[1] = __builtin_amdgcn_mfma_f32_16x16x32_bf16(afh, qfh[1][dc], acc[1], 0, 0, 0);
      acc[1] = __builtin_amdgcn_mfma_f32_16x16x32_bf16(afh, qfl[1][dc], acc[1], 0, 0, 0);
      acc[1] = __builtin_amdgcn_mfma_f32_16x16x32_bf16(afl, qfh[1][dc], acc[1], 0, 0, 0);
    }
    __builtin_amdgcn_s_setprio(0);

    // e = exp(s/16) -> etile[cur] (bf16, swizzled) + rowsum
#pragma unroll
    for (int qt = 0; qt < 2; ++qt) {
      f32x4 e;
#pragma unroll
      for (int r = 0; r < 4; ++r) e[r] = __expf(acc[qt][r] * 0.0625f);
      rs[qt] += e[0] + e[1] + e[2] + e[3];
      unsigned lo = (unsigned)(unsigned short)f2bf(e[0]) |
                    ((unsigned)(unsigned short)f2bf(e[1]) << 16);
      unsigned hi2 = (unsigned)(unsigned short)f2bf(e[2]) |
                     ((unsigned)(unsigned short)f2bf(e[3]) << 16);
      const int row = wq2 * 32 + qt * 16 + lr;
      const int colb = (wk4 * 16 + g * 4) * 2;
      const int ad = (row * 128 + colb) ^ ((row & 7) << 4);
      *(uint2*)(etile[cur] + ad) = make_uint2(lo, hi2);
      acc[qt] = (f32x4)0.f;
    }

    asm volatile("s_waitcnt lgkmcnt(0)" ::: "memory");  // etile writes done
    __builtin_amdgcn_s_barrier();        // D: etile[cur] valid; kb reads done
    __builtin_amdgcn_sched_barrier(0);

    // stage(kt+2) into the buffer tile kt just finished with
    if (kt < 62) STAGE(kt + 2, kbuf + cur * 65536);

    // ecopy: unnormalized e-bf16 -> EB (top half of weights region)
    {
      const char* et = etile[cur];
      const int p = tid * 16;
      const int row = p >> 7, cb = p & 127;
      uint32x4 v = *(const uint32x4*)(et + (p ^ ((row & 7) << 4)));
      *(uint32x4*)(EB + (size_t)row * 8192 + kt * 128 + cb) = v;
    }

    // PV(kt): A = e-tile from LDS, B = vb registers
    __builtin_amdgcn_s_setprio(1);
#pragma unroll
    for (int kk = 0; kk < 2; ++kk) {
      short8 ea0, ea1;
      {
        const int row = qh_pv * 32 + lr;
        ea0 = *(const short8*)(etile[cur] + ((row * 128 + kk * 64 + g * 16) ^ ((row & 7) << 4)));
      }
      {
        const int row = qh_pv * 32 + 16 + lr;
        ea1 = *(const short8*)(etile[cur] + ((row * 128 + kk * 64 + g * 16) ^ ((row & 7) << 4)));
      }
#pragma unroll
      for (int dt = 0; dt < 4; ++dt) {
        accv[0][dt] = __builtin_amdgcn_mfma_f32_16x16x32_bf16(ea0, vb[kk][dt], accv[0][dt], 0, 0, 0);
        accv[1][dt] = __builtin_amdgcn_mfma_f32_16x16x32_bf16(ea1, vb[kk][dt], accv[1][dt], 0, 0, 0);
      }
    }
    __builtin_amdgcn_s_setprio(0);
  }

  // ---- rowsums -> lsum_l
#pragma unroll
  for (int qt = 0; qt < 2; ++qt) {
    rs[qt] += __shfl_xor(rs[qt], 16, 64);
    rs[qt] += __shfl_xor(rs[qt], 32, 64);
  }
  if (lane < 16) {
    part[wk4][wq2 * 32 + lane] = rs[0];
    part[wk4][wq2 * 32 + 16 + lane] = rs[1];
  }
  __syncthreads();   // full drain (EB stores incl.) + part visible
  if (tid < 64)
    lsum_l[tid] = part[0][tid] + part[1][tid] + part[2][tid] + part[3][tid];
  __syncthreads();

  // ---- copy e rows 62,63 into LDS (their EB copies are overwritten last)
#pragma unroll
  for (int i = 0; i < 2; ++i) {
    const int p = i * 8192 + tid * 16;
    *(uint32x4*)(kbuf + p) = *(const uint32x4*)(EB + (size_t)62 * 8192 + p);
  }

  // ---- normalized output write
  {
    float* ob = out + (size_t)b * S_ * D_;
    float rv[2][4];
#pragma unroll
    for (int qt = 0; qt < 2; ++qt)
#pragma unroll
      for (int r = 0; r < 4; ++r)
        rv[qt][r] = 1.0f / lsum_l[qh_pv * 32 + qt * 16 + g * 4 + r];
#pragma unroll
    for (int qt = 0; qt < 2; ++qt)
#pragma unroll
      for (int dt = 0; dt < 4; ++dt)
#pragma unroll
        for (int r = 0; r < 4; ++r) {
          const int q = qbase + qh_pv * 32 + qt * 16 + g * 4 + r;
          ob[(size_t)q * D_ + dh_pv * 64 + dt * 16 + lr] = accv[qt][dt][r] * rv[qt][r];
        }
  }
  __syncthreads();

  // ---- phased in-place normalize sweep: e-bf16 (EB) -> f32 weights (WB)
  const int pr0[6] = {0, 32, 48, 56, 60, 62};
  const int pr1[6] = {32, 48, 56, 60, 62, 64};
  float* WBf = (float*)WB;
#pragma unroll 1
  for (int ph = 0; ph < 6; ++ph) {
    for (int r = pr0[ph] + w; r < pr1[ph]; r += 8) {
      const float rinv = 1.0f / lsum_l[r];
      const short* erow = (r >= 62) ? (const short*)(kbuf + (size_t)(r - 62) * 8192)
                                    : (const short*)(EB + (size_t)r * 8192);
      float* wrow = WBf + (size_t)r * 4096;
      for (int c = lane * 8; c < 4096; c += 512) {
        short8 ev = *(const short8*)(erow + c);
        f32x4 o0, o1;
#pragma unroll
        for (int j = 0; j < 4; ++j) o0[j] = bf2f(ev[j]) * rinv;
#pragma unroll
        for (int j = 0; j < 4; ++j) o1[j] = bf2f(ev[4 + j]) * rinv;
        *(f32x4*)(wrow + c) = o0;
        *(f32x4*)(wrow + c + 4) = o1;
      }
    }
    __syncthreads();
  }
}

// ---------------------------------------------------------------- launch
extern "C" void kernel_launch(void* const* d_in, const int* in_sizes, int n_in,
                              void* d_out, int out_size, void* d_ws, size_t ws_size,
                              hipStream_t stream) {
  const float* x  = (const float*)d_in[0];
  const float* wq = (const float*)d_in[1];
  const float* wk = (const float*)d_in[2];
  const float* wv = (const float*)d_in[3];

  float* out = (float*)d_out;                    // [B][S][D]
  float* wts = out + (size_t)B_ * S_ * D_;       // [B][S][S]

  // workspace layout (~63.5 MB)
  short* xh = (short*)d_ws;
  short* xl = xh + NQ;
  short* qh = xl + NQ;
  short* ql = qh + NQ;
  short* kh = ql + NQ;
  short* kl = kh + NQ;
  short* vt = kl + NQ;                 // [B][D][S] bf16
  short* wh = vt + NQ;                 // [3][D][D] bf16
  short* wl = wh + 3 * NW;
  float* ctab = (float*)(wl + 3 * NW); // [S][128] (cos,sin) fp32

  k0_split<<<dim3((NQ + 3 * NW + NTAB) / 256), 256, 0, stream>>>(
      x, wq, wk, wv, xh, xl, wh, wl, ctab);
  k1_proj<<<dim3(B_ * S_ / 64, 3), 256, 0, stream>>>(
      xh, xl, wh, wl, ctab, qh, ql, kh, kl, vt);
  k2_fused<<<dim3(B_ * S_ / 64), 512, 0, stream>>>(
      qh, ql, kh, kl, vt, wts, out);
}

// Round 7
// 480.423 us; speedup vs baseline: 1.3831x; 1.0697x over previous
//
#include <hip/hip_runtime.h>
#include <hip/hip_bf16.h>
#include <stdint.h>

// RoPEDemoAttention on MI355X (gfx950)
// B=4, S=4096, D=256. fp32 in/out.
// K0: split fp32 -> bf16 hi/lo + RoPE cos/sin table.
// K1: Q/K/V projections via 3-pass split-bf16 MFMA + RoPE (R3 version).
// K2 (fused, R3 skeleton; R7: score-waves are 16q x 32keys so Q-frags fit
//     in 64 VGPR -> no per-tile Q rematerialization; launch_bounds(512,2)):
//   dbuf K-tile LDS + dbuf e-tile, ONE barrier per k-tile:
//     stage(kt+1) -> ecopy+PV(kt-1) -> scores(kt) -> exp -> barrier
//   then rowsums, normalized out, phased in-place e->weights sweep.

#define B_ 4
#define S_ 4096
#define D_ 256
#define NQ 4194304   // B_*S_*D_
#define NW 65536     // D_*D_
#define NTAB 524288  // S_*128 table entries (cos,sin pairs)

typedef __attribute__((ext_vector_type(4))) float f32x4;
typedef __attribute__((ext_vector_type(8))) short short8;
typedef __attribute__((ext_vector_type(4))) short short4v;
typedef __attribute__((ext_vector_type(4))) unsigned uint32x4;

__device__ __forceinline__ short f2bf(float f) {
  unsigned u = __builtin_bit_cast(unsigned, f);
  u += 0x7fffu + ((u >> 16) & 1u);   // RNE
  return (short)(u >> 16);
}
__device__ __forceinline__ float bf2f(short h) {
  unsigned u = ((unsigned)(unsigned short)h) << 16;
  return __builtin_bit_cast(float, u);
}

__device__ __forceinline__ void gload16(const void* g, void* l) {
  __builtin_amdgcn_global_load_lds(
      (const __attribute__((address_space(1))) unsigned*)g,
      (__attribute__((address_space(3))) unsigned*)l, 16, 0, 0);
}

// ------------------------------------------------ K0: split + RoPE table
__global__ __launch_bounds__(256) void k0_split(
    const float* __restrict__ x, const float* __restrict__ wq,
    const float* __restrict__ wk, const float* __restrict__ wv,
    short* __restrict__ xh, short* __restrict__ xl,
    short* __restrict__ wh, short* __restrict__ wl,
    float* __restrict__ ctab) {
  int idx = blockIdx.x * 256 + threadIdx.x;  // grid = NQ + 3*NW + NTAB
  if (idx < NQ) {
    float v = x[idx];
    short hi = f2bf(v);
    xh[idx] = hi;
    xl[idx] = f2bf(v - bf2f(hi));
  } else if (idx < NQ + 3 * NW) {
    int r = idx - NQ;
    int m = r >> 16;
    int e = r & (NW - 1);
    const float* w = (m == 0) ? wq : (m == 1) ? wk : wv;
    float v = w[e];
    short hi = f2bf(v);
    wh[r] = hi;
    wl[r] = f2bf(v - bf2f(hi));
  } else {
    int t = idx - NQ - 3 * NW;          // t < NTAB
    int s = t >> 7, j = t & 127;
    float invf = __expf(-0.07195578415606394f * (float)j); // 10000^(-j/128)
    float sn, cs;
    sincosf((float)s * invf, &sn, &cs);
    ctab[2 * t] = cs;
    ctab[2 * t + 1] = sn;
  }
}

// ------------------------------------------------------- K1: proj + RoPE
__global__ __launch_bounds__(256) void k1_proj(
    const short* __restrict__ xh, const short* __restrict__ xl,
    const short* __restrict__ wh, const short* __restrict__ wl,
    const float* __restrict__ ctab,
    short* __restrict__ qh, short* __restrict__ ql,
    short* __restrict__ kh, short* __restrict__ kl,
    short* __restrict__ vt) {
  const int m = blockIdx.y;                 // 0=q 1=k 2=v
  const int b = blockIdx.x >> 6;
  const int sbase = (blockIdx.x & 63) << 6; // 64-row tile
  const int tid = threadIdx.x;
  const int w = tid >> 6;
  const int lane = tid & 63;
  const int lr = lane & 15;
  const int g = lane >> 4;

  const int srow = sbase + w * 16 + lr;     // A-frag row
  const short* xhp = xh + ((size_t)(b * S_ + srow)) * D_;
  const short* xlp = xl + ((size_t)(b * S_ + srow)) * D_;
  const short* whm = wh + m * NW;
  const short* wlm = wl + m * NW;

  f32x4 acc[16];
#pragma unroll
  for (int i = 0; i < 16; ++i) acc[i] = (f32x4)0.f;

#pragma unroll
  for (int dc = 0; dc < 8; ++dc) {
    const int d = dc * 32 + g * 8;
    short8 ah = *(const short8*)(xhp + d);
    short8 al = *(const short8*)(xlp + d);
#pragma unroll
    for (int ct = 0; ct < 16; ++ct) {
      const int e = ct * 16 + lr;
      short8 bh = *(const short8*)(whm + e * D_ + d);
      short8 bl = *(const short8*)(wlm + e * D_ + d);
      acc[ct] = __builtin_amdgcn_mfma_f32_16x16x32_bf16(ah, bh, acc[ct], 0, 0, 0);
      acc[ct] = __builtin_amdgcn_mfma_f32_16x16x32_bf16(ah, bl, acc[ct], 0, 0, 0);
      acc[ct] = __builtin_amdgcn_mfma_f32_16x16x32_bf16(al, bh, acc[ct], 0, 0, 0);
    }
  }

  const int s0 = sbase + w * 16 + g * 4;    // C/D row base
  if (m == 2) {
#pragma unroll
    for (int ct = 0; ct < 16; ++ct) {
      const int e = ct * 16 + lr;
      short4v pk;
#pragma unroll
      for (int r = 0; r < 4; ++r) pk[r] = f2bf(acc[ct][r]);
      *(short4v*)(vt + ((size_t)(b * D_ + e)) * S_ + s0) = pk;
    }
  } else {
    short* oh = (m == 0) ? qh : kh;
    short* ol = (m == 0) ? ql : kl;
#pragma unroll
    for (int ct = 0; ct < 16; ++ct) {
      const int e = ct * 16 + lr;
      const float sgn = (e & 1) ? 1.0f : -1.0f;  // rotate_half sign
#pragma unroll
      for (int r = 0; r < 4; ++r) {
        float v = acc[ct][r];
        float p = __shfl_xor(v, 1, 64);          // partner e^1, same s
        const float2 cs2 = *(const float2*)(ctab + ((size_t)((s0 + r) << 7) + (e & 127)) * 2);
        float q2 = v * cs2.x + sgn * p * cs2.y;
        short hi = f2bf(q2);
        size_t off = ((size_t)(b * S_ + s0 + r)) * D_ + e;
        oh[off] = hi;
        ol[off] = f2bf(q2 - bf2f(hi));
      }
    }
  }
}

// ------------- K2 fused: pipelined scores + e-store + PV + sweep
__global__ __launch_bounds__(512, 2) void k2_fused(
    const short* __restrict__ qh, const short* __restrict__ ql,
    const short* __restrict__ kh, const short* __restrict__ kl,
    const short* __restrict__ vt,
    float* __restrict__ wts, float* __restrict__ out) {
  __shared__ __align__(16) char kbuf[131072];   // [2][Khi 32K | Klo 32K]
  __shared__ __align__(16) char etile[2][8192]; // e bf16 [64][64], swizzled
  __shared__ float part[2][64];
  __shared__ float lsum_l[64];

  const int bid = blockIdx.x;
  const int swz = (bid & 7) * 32 + (bid >> 3); // XCD-contiguous (256 = 8*32)
  const int b = swz >> 6;
  const int qbase = (swz & 63) << 6;
  const int tid = threadIdx.x;
  const int w = tid >> 6;        // 8 waves
  const int lane = tid & 63;
  const int lr = lane & 15;
  const int g = lane >> 4;
  const int qg = w & 3;          // scores: which 16 q-rows
  const int kg = w >> 2;         // scores: which 32 keys of 64-key tile
  const int qh_pv = w & 1;       // PV: q 32-half
  const int dh_pv = w >> 1;      // PV: d 64-quarter

  // Q hi/lo fragments (B-operand): 16 q-rows/wave -> 64 VGPR, stays resident
  short8 qfh[8], qfl[8];
  {
    const int qrow = qbase + qg * 16 + lr;
    const short* ph = qh + ((size_t)(b * S_ + qrow)) * D_;
    const short* pl = ql + ((size_t)(b * S_ + qrow)) * D_;
#pragma unroll
    for (int dc = 0; dc < 8; ++dc) {
      qfh[dc] = *(const short8*)(ph + dc * 32 + g * 8);
      qfl[dc] = *(const short8*)(pl + dc * 32 + g * 8);
    }
  }

  f32x4 acc[2];                  // 2 key-subtiles (16 keys each)
  acc[0] = (f32x4)0.f; acc[1] = (f32x4)0.f;
  f32x4 accv[2][4];
#pragma unroll
  for (int qt = 0; qt < 2; ++qt)
#pragma unroll
    for (int dt = 0; dt < 4; ++dt) accv[qt][dt] = (f32x4)0.f;
  float rs = 0.f;

  const char* khb = (const char*)(kh + (size_t)b * S_ * D_);
  const char* klb = (const char*)(kl + (size_t)b * S_ * D_);
  const short* vtb = vt + (size_t)b * D_ * S_;
  const int swx = (lane & 7) << 4;         // K-LDS swizzle: (key&7)<<4

  // block's weights region (1 MiB); e-bf16 scratch in its top half
  char* WB = (char*)(wts + ((size_t)(b * S_ + qbase)) * S_);
  char* EB = WB + 524288;

  // prologue: stage K-tile 0 into kbuf[0]
#pragma unroll
  for (int i = 0; i < 4; ++i) {
    const int p = i * 8192 + tid * 16;
    const int xo = p ^ (((p >> 9) & 7) << 4);
    gload16(khb + xo, kbuf + p);
    gload16(klb + xo, kbuf + 32768 + p);
  }
  __syncthreads();

  for (int kt = 0; kt < 64; ++kt) {
    const int cur = kt & 1;
    const char* kb = kbuf + cur * 65536;

    // 1. stage next K-tile into the other buffer (lands by end barrier)
    if (kt < 63) {
      const char* sh = khb + (size_t)(kt + 1) * 32768;
      const char* sl = klb + (size_t)(kt + 1) * 32768;
      char* kn = kbuf + (cur ^ 1) * 65536;
#pragma unroll
      for (int i = 0; i < 4; ++i) {
        const int p = i * 8192 + tid * 16;
        const int xo = p ^ (((p >> 9) & 7) << 4);
        gload16(sh + xo, kn + p);
        gload16(sl + xo, kn + 32768 + p);
      }
    }

    // 2. e-copy + PV of the PREVIOUS tile (etile[cur^1])
    if (kt > 0) {
      const char* et = etile[cur ^ 1];
      {
        const int p = tid * 16;            // 512 thr * 16B = 8 KB
        const int row = p >> 7, cb = p & 127;
        uint32x4 v = *(const uint32x4*)(et + (p ^ ((row & 7) << 4)));
        *(uint32x4*)(EB + (size_t)row * 8192 + (kt - 1) * 128 + cb) = v;
      }
      __builtin_amdgcn_s_setprio(1);
#pragma unroll
      for (int kk = 0; kk < 2; ++kk) {
        short8 ea0, ea1;
        {
          const int row = qh_pv * 32 + lr;
          ea0 = *(const short8*)(et + ((row * 128 + kk * 64 + g * 16) ^ ((row & 7) << 4)));
        }
        {
          const int row = qh_pv * 32 + 16 + lr;
          ea1 = *(const short8*)(et + ((row * 128 + kk * 64 + g * 16) ^ ((row & 7) << 4)));
        }
#pragma unroll
        for (int dt = 0; dt < 4; ++dt) {
          const int d = dh_pv * 64 + dt * 16 + lr;
          short8 vb = *(const short8*)(vtb + (size_t)d * S_ + (kt - 1) * 64 + kk * 32 + g * 8);
          accv[0][dt] = __builtin_amdgcn_mfma_f32_16x16x32_bf16(ea0, vb, accv[0][dt], 0, 0, 0);
          accv[1][dt] = __builtin_amdgcn_mfma_f32_16x16x32_bf16(ea1, vb, accv[1][dt], 0, 0, 0);
        }
      }
      __builtin_amdgcn_s_setprio(0);
    }

    // 3. scores: 3-pass split bf16, S^T = K * Q^T (16q x 32keys per wave)
    __builtin_amdgcn_s_setprio(1);
#pragma unroll
    for (int dc = 0; dc < 8; ++dc) {
      short8 afh[2], afl[2];
#pragma unroll
      for (int ks = 0; ks < 2; ++ks) {
        const int row = kg * 32 + ks * 16 + lr;
        const int x = (row * 512 + dc * 64 + g * 16) ^ swx;
        afh[ks] = *(const short8*)(kb + x);
        afl[ks] = *(const short8*)(kb + 32768 + x);
      }
#pragma unroll
      for (int ks = 0; ks < 2; ++ks) {
        acc[ks] = __builtin_amdgcn_mfma_f32_16x16x32_bf16(afh[ks], qfh[dc], acc[ks], 0, 0, 0);
        acc[ks] = __builtin_amdgcn_mfma_f32_16x16x32_bf16(afh[ks], qfl[dc], acc[ks], 0, 0, 0);
        acc[ks] = __builtin_amdgcn_mfma_f32_16x16x32_bf16(afl[ks], qfh[dc], acc[ks], 0, 0, 0);
      }
    }
    __builtin_amdgcn_s_setprio(0);

    // 4. e = exp(s/16) -> etile[cur] (bf16, swizzled) + rowsum
#pragma unroll
    for (int ks = 0; ks < 2; ++ks) {
      f32x4 e;
#pragma unroll
      for (int r = 0; r < 4; ++r) e[r] = __expf(acc[ks][r] * 0.0625f);
      rs += e[0] + e[1] + e[2] + e[3];
      unsigned lo = (unsigned)(unsigned short)f2bf(e[0]) |
                    ((unsigned)(unsigned short)f2bf(e[1]) << 16);
      unsigned hi2 = (unsigned)(unsigned short)f2bf(e[2]) |
                     ((unsigned)(unsigned short)f2bf(e[3]) << 16);
      const int row = qg * 16 + lr;
      const int colb = (kg * 32 + ks * 16 + g * 4) * 2;
      const int ad = (row * 128 + colb) ^ ((row & 7) << 4);
      *(uint2*)(etile[cur] + ad) = make_uint2(lo, hi2);
      acc[ks] = (f32x4)0.f;
    }
    __syncthreads();   // ONE barrier per tile
  }

  // ---- tail: e-copy + PV of tile 63 (etile[1])
  {
    const char* et = etile[1];
    {
      const int p = tid * 16;
      const int row = p >> 7, cb = p & 127;
      uint32x4 v = *(const uint32x4*)(et + (p ^ ((row & 7) << 4)));
      *(uint32x4*)(EB + (size_t)row * 8192 + 63 * 128 + cb) = v;
    }
#pragma unroll
    for (int kk = 0; kk < 2; ++kk) {
      short8 ea0, ea1;
      {
        const int row = qh_pv * 32 + lr;
        ea0 = *(const short8*)(et + ((row * 128 + kk * 64 + g * 16) ^ ((row & 7) << 4)));
      }
      {
        const int row = qh_pv * 32 + 16 + lr;
        ea1 = *(const short8*)(et + ((row * 128 + kk * 64 + g * 16) ^ ((row & 7) << 4)));
      }
#pragma unroll
      for (int dt = 0; dt < 4; ++dt) {
        const int d = dh_pv * 64 + dt * 16 + lr;
        short8 vb = *(const short8*)(vtb + (size_t)d * S_ + 63 * 64 + kk * 32 + g * 8);
        accv[0][dt] = __builtin_amdgcn_mfma_f32_16x16x32_bf16(ea0, vb, accv[0][dt], 0, 0, 0);
        accv[1][dt] = __builtin_amdgcn_mfma_f32_16x16x32_bf16(ea1, vb, accv[1][dt], 0, 0, 0);
      }
    }
  }

  // ---- rowsums -> lsum_l (lanes with same lr across g hold same q-row)
  rs += __shfl_xor(rs, 16, 64);
  rs += __shfl_xor(rs, 32, 64);
  if (lane < 16) part[kg][qg * 16 + lane] = rs;
  __syncthreads();
  if (tid < 64) lsum_l[tid] = part[0][tid] + part[1][tid];
  __syncthreads();

  // ---- copy e rows 62,63 into LDS (their EB copies are overwritten last)
#pragma unroll
  for (int i = 0; i < 2; ++i) {
    const int p = i * 8192 + tid * 16;
    *(uint32x4*)(kbuf + p) = *(const uint32x4*)(EB + (size_t)62 * 8192 + p);
  }

  // ---- normalized output write
  {
    float* ob = out + (size_t)b * S_ * D_;
    float rv[2][4];
#pragma unroll
    for (int qt = 0; qt < 2; ++qt)
#pragma unroll
      for (int r = 0; r < 4; ++r)
        rv[qt][r] = 1.0f / lsum_l[qh_pv * 32 + qt * 16 + g * 4 + r];
#pragma unroll
    for (int qt = 0; qt < 2; ++qt)
#pragma unroll
      for (int dt = 0; dt < 4; ++dt)
#pragma unroll
        for (int r = 0; r < 4; ++r) {
          const int q = qbase + qh_pv * 32 + qt * 16 + g * 4 + r;
          ob[(size_t)q * D_ + dh_pv * 64 + dt * 16 + lr] = accv[qt][dt][r] * rv[qt][r];
        }
  }
  __syncthreads();

  // ---- phased in-place normalize sweep: e-bf16 (EB) -> f32 weights (WB)
  const int pr0[6] = {0, 32, 48, 56, 60, 62};
  const int pr1[6] = {32, 48, 56, 60, 62, 64};
  float* WBf = (float*)WB;
#pragma unroll 1
  for (int ph = 0; ph < 6; ++ph) {
    for (int r = pr0[ph] + w; r < pr1[ph]; r += 8) {
      const float rinv = 1.0f / lsum_l[r];
      const short* erow = (r >= 62) ? (const short*)(kbuf + (size_t)(r - 62) * 8192)
                                    : (const short*)(EB + (size_t)r * 8192);
      float* wrow = WBf + (size_t)r * 4096;
      for (int c = lane * 8; c < 4096; c += 512) {
        short8 ev = *(const short8*)(erow + c);
        f32x4 o0, o1;
#pragma unroll
        for (int j = 0; j < 4; ++j) o0[j] = bf2f(ev[j]) * rinv;
#pragma unroll
        for (int j = 0; j < 4; ++j) o1[j] = bf2f(ev[4 + j]) * rinv;
        *(f32x4*)(wrow + c) = o0;
        *(f32x4*)(wrow + c + 4) = o1;
      }
    }
    __syncthreads();
  }
}

// ---------------------------------------------------------------- launch
extern "C" void kernel_launch(void* const* d_in, const int* in_sizes, int n_in,
                              void* d_out, int out_size, void* d_ws, size_t ws_size,
                              hipStream_t stream) {
  const float* x  = (const float*)d_in[0];
  const float* wq = (const float*)d_in[1];
  const float* wk = (const float*)d_in[2];
  const float* wv = (const float*)d_in[3];

  float* out = (float*)d_out;                    // [B][S][D]
  float* wts = out + (size_t)B_ * S_ * D_;       // [B][S][S]

  // workspace layout (~63.5 MB)
  short* xh = (short*)d_ws;
  short* xl = xh + NQ;
  short* qh = xl + NQ;
  short* ql = qh + NQ;
  short* kh = ql + NQ;
  short* kl = kh + NQ;
  short* vt = kl + NQ;                 // [B][D][S] bf16
  short* wh = vt + NQ;                 // [3][D][D] bf16
  short* wl = wh + 3 * NW;
  float* ctab = (float*)(wl + 3 * NW); // [S][128] (cos,sin) fp32

  k0_split<<<dim3((NQ + 3 * NW + NTAB) / 256), 256, 0, stream>>>(
      x, wq, wk, wv, xh, xl, wh, wl, ctab);
  k1_proj<<<dim3(B_ * S_ / 64, 3), 256, 0, stream>>>(
      xh, xl, wh, wl, ctab, qh, ql, kh, kl, vt);
  k2_fused<<<dim3(B_ * S_ / 64), 512, 0, stream>>>(
      qh, ql, kh, kl, vt, wts, out);
}